// Round 9
// baseline (210.508 us; speedup 1.0000x reference)
//
#include <hip/hip_runtime.h>
#include <hip/hip_bf16.h>

// B=2, N=2048, E=1024, H=16, HD=64. Inputs fp32, output fp32.
// ws (32 MiB): kbuf qbuf vbuf sabuf (bf16, 8 MB each).
// Wqkv_t (6 MB) in sabuf region until attn; Wout_t (2 MB) in kbuf after attn.
// d_out (16 MB) as scratch: xbf = first 8 MB (until qkv done),
// vtb (V transposed [bh][d][n]) = second 8 MB (until out_mfma).
#define Bz 2
#define Nn 2048
#define Ee 1024
#define Hh 16
#define HD 64

typedef unsigned short u16;
typedef unsigned int u32;

typedef __bf16 bf16x8 __attribute__((ext_vector_type(8)));
typedef float f32x4 __attribute__((ext_vector_type(4)));

__device__ __forceinline__ float bf2f(u16 u) {
    u32 v = ((u32)u) << 16;
    return __builtin_bit_cast(float, v);
}
__device__ __forceinline__ u16 f2bf(float f) {
    u32 i = __builtin_bit_cast(u32, f);
    u32 r = (i + 0x7FFFu + ((i >> 16) & 1u)) >> 16;  // RNE
    return (u16)r;
}
__device__ __forceinline__ u32 pack2(float a, float b) {
    return (u32)f2bf(a) | ((u32)f2bf(b) << 16);
}
__device__ __forceinline__ bf16x8 ld_frag(const u16* p) {
    return __builtin_bit_cast(bf16x8, *(const uint4*)p);
}
__device__ __forceinline__ f32x4 zero4() {
    f32x4 z; z[0]=0.f; z[1]=0.f; z[2]=0.f; z[3]=0.f; return z;
}

// async 16B/lane global->LDS DMA; LDS dest = (uniform base) + lane*16.
__device__ __forceinline__ void async_copy16(const u16* g, u16* l) {
    __builtin_amdgcn_global_load_lds(
        (const __attribute__((address_space(1))) u32*)g,
        (__attribute__((address_space(3))) u32*)l, 16, 0, 0);
}

__global__ void ws_diag(float* out, float code) { out[0] = code; }

// ---------------------------------------------------------------------------
// x fp32 [4096*1024] -> bf16 row-major, into d_out scratch (first half).
// ---------------------------------------------------------------------------
__global__ __launch_bounds__(256) void convert_x(
    const float* __restrict__ x, u16* __restrict__ xbf)
{
    size_t idx = ((size_t)blockIdx.x * 256 + threadIdx.x) * 8;
    float4 f0 = *(const float4*)(x + idx);
    float4 f1 = *(const float4*)(x + idx + 4);
    uint4 pk;
    pk.x = pack2(f0.x, f0.y); pk.y = pack2(f0.z, f0.w);
    pk.z = pack2(f1.x, f1.y); pk.w = pack2(f1.z, f1.w);
    *(uint4*)(xbf + idx) = pk;
}

// ---------------------------------------------------------------------------
// Transpose f32 [R][C] -> bf16 [C][R], per z-slice. R,C multiples of 64.
// ---------------------------------------------------------------------------
__global__ __launch_bounds__(256) void transpose_f32_bf16(
    const float* __restrict__ src, u16* __restrict__ dst, int R, int C)
{
    const int r0 = blockIdx.x * 64, c0 = blockIdx.y * 64;
    const size_t zoff = (size_t)blockIdx.z * R * C;
    src += zoff; dst += zoff;
    const int tid = threadIdx.x;

    __shared__ float T[64][65];
    {
        int tr = tid >> 2, tc = (tid & 3) * 16;
        const float* s = src + (size_t)(r0 + tr) * C + c0 + tc;
#pragma unroll
        for (int j = 0; j < 4; ++j) {
            float4 v = ((const float4*)s)[j];
            T[tr][tc + 4 * j + 0] = v.x; T[tr][tc + 4 * j + 1] = v.y;
            T[tr][tc + 4 * j + 2] = v.z; T[tr][tc + 4 * j + 3] = v.w;
        }
    }
    __syncthreads();
    {
        int cc = tid >> 2, rr = (tid & 3) * 16;
        u16* d = dst + (size_t)(c0 + cc) * R + r0 + rr;
        u32 w[8];
#pragma unroll
        for (int i = 0; i < 8; ++i)
            w[i] = pack2(T[rr + 2 * i][cc], T[rr + 2 * i + 1][cc]);
        *(uint4*)(d)     = make_uint4(w[0], w[1], w[2], w[3]);
        *(uint4*)(d + 8) = make_uint4(w[4], w[5], w[6], w[7]);
    }
}

// ---------------------------------------------------------------------------
// Transpose bf16 [2048 n][64 d] -> [64 d][2048 n] per bh slice (V -> V^T).
// grid (32 n-tiles, 32 bh).
// ---------------------------------------------------------------------------
__global__ __launch_bounds__(256) void transpose_v(
    const u16* __restrict__ src, u16* __restrict__ dst)
{
    const int n0 = blockIdx.x * 64;
    const size_t z = blockIdx.y;
    src += z * (size_t)Nn * HD;
    dst += z * (size_t)HD * Nn;
    const int tid = threadIdx.x;

    __shared__ u16 T[64][66];
    {
        int tr = tid >> 2, tc = (tid & 3) * 16;
        const u16* s = src + (size_t)(n0 + tr) * HD + tc;
        *(uint4*)&T[tr][tc]     = *(const uint4*)(s);
        *(uint4*)&T[tr][tc + 8] = *(const uint4*)(s + 8);
    }
    __syncthreads();
    {
        int cc = tid >> 2, rr = (tid & 3) * 16;  // cc = d, rr = n base
        u32 w[8];
#pragma unroll
        for (int i = 0; i < 8; ++i)
            w[i] = (u32)T[rr + 2 * i][cc] | ((u32)T[rr + 2 * i + 1][cc] << 16);
        u16* d = dst + (size_t)cc * Nn + n0 + rr;
        *(uint4*)(d)     = make_uint4(w[0], w[1], w[2], w[3]);
        *(uint4*)(d + 8) = make_uint4(w[4], w[5], w[6], w[7]);
    }
}

// ---------------------------------------------------------------------------
// Kernel 1: QKV projection, MFMA 16x16x32, async staging (unchanged R8).
// ---------------------------------------------------------------------------
__global__ __launch_bounds__(256) void qkv_mfma(
    const u16* __restrict__ xbf, const u16* __restrict__ Wt,
    const float* __restrict__ bias,
    u16* __restrict__ kbuf, u16* __restrict__ qbuf, u16* __restrict__ vbuf)
{
    const int mt = blockIdx.x;   // 0..63
    const int h  = blockIdx.y;   // 0..15
    const int tid = threadIdx.x;
    const int lane = tid & 63, wid = tid >> 6;
    const int quad = lane >> 4, l15 = lane & 15;

    __shared__ u16 As[64 * 64];
    __shared__ u16 Bs[192 * 64];

    f32x4 acc[4][3];
#pragma unroll
    for (int mi = 0; mi < 4; ++mi)
#pragma unroll
        for (int ni = 0; ni < 3; ++ni) acc[mi][ni] = zero4();

    const u16* xb = xbf + (size_t)mt * 64 * Ee;
    const u16* wtb = Wt + (size_t)h * 192 * 1024;

    const int arowl = lane >> 3;
    const int jj = (lane & 7) ^ arowl;

    for (int kb = 0; kb < 16; ++kb) {
        __syncthreads();
#pragma unroll
        for (int i = 0; i < 2; ++i) {
            int rbase = (wid * 2 + i) * 8;
            const u16* g = xb + (size_t)(rbase + arowl) * Ee + kb * 64 + jj * 8;
            async_copy16(g, &As[(wid * 2 + i) * 512]);
        }
#pragma unroll
        for (int i = 0; i < 6; ++i) {
            int rbase = (wid * 6 + i) * 8;
            const u16* g = wtb + (size_t)(rbase + arowl) * 1024 + kb * 64 + jj * 8;
            async_copy16(g, &Bs[(wid * 6 + i) * 512]);
        }
        __syncthreads();

#pragma unroll
        for (int kk0 = 0; kk0 < 2; ++kk0) {
            const int pos = ((kk0 * 4 + quad) ^ (l15 & 7)) * 8;
            bf16x8 af[4], bf[3];
#pragma unroll
            for (int mi = 0; mi < 4; ++mi)
                af[mi] = ld_frag(&As[(mi * 16 + l15) * 64 + pos]);
#pragma unroll
            for (int ni = 0; ni < 3; ++ni)
                bf[ni] = ld_frag(&Bs[(wid * 48 + ni * 16 + l15) * 64 + pos]);
#pragma unroll
            for (int mi = 0; mi < 4; ++mi)
#pragma unroll
                for (int ni = 0; ni < 3; ++ni)
                    acc[mi][ni] = __builtin_amdgcn_mfma_f32_16x16x32_bf16(
                        af[mi], bf[ni], acc[mi][ni], 0, 0, 0);
        }
    }

#pragma unroll
    for (int ni = 0; ni < 3; ++ni) {
        int col = wid * 48 + ni * 16 + l15;   // 0..191
        int ft = col >> 6, d = col & 63;
        u16* dst = (ft == 0) ? kbuf : (ft == 1) ? qbuf : vbuf;
        float bv = bias[h * 192 + col];
#pragma unroll
        for (int mi = 0; mi < 4; ++mi)
#pragma unroll
            for (int r = 0; r < 4; ++r) {
                int gm = mt * 64 + mi * 16 + quad * 4 + r;
                int bb = gm >> 11, n = gm & (Nn - 1);
                dst[(((size_t)(bb * Hh + h)) * Nn + n) * HD + d] =
                    f2bf(acc[mi][ni][r] + bv);
            }
    }
}

// ---------------------------------------------------------------------------
// Kernel 2 v3: causal flash attention, transposed-S, MFMA 16x16x32,
// double-buffered async K/V^T staging (XOR-swizzled, unpadded LDS 32 KB).
// Block = paired q-tiles (p, 31-p); prefetch kt+1 issued after iter barrier.
// Softmax in log2 domain (exp2).
// ---------------------------------------------------------------------------
__global__ __launch_bounds__(256) void attn2(
    const u16* __restrict__ qbuf, const u16* __restrict__ kbuf,
    const u16* __restrict__ vtb, u16* __restrict__ sabuf)
{
    const int p  = blockIdx.x;   // 0..15 (pair index)
    const int bh = blockIdx.y;   // 0..31
    const int b = bh >> 4, h = bh & 15;
    const int tid = threadIdx.x;
    const int lane = tid & 63, wid = tid >> 6;
    const int l15 = lane & 15, quad = lane >> 4;

    __shared__ u16 KsL[2][4096];   // [buf][key 64][d 64] chunk-swizzled
    __shared__ u16 VtL[2][4096];   // [buf][d 64][key 64] chunk-swizzled

    const u16* qb = qbuf + (size_t)bh * Nn * HD;
    const u16* kb = kbuf + (size_t)bh * Nn * HD;
    const u16* vt = vtb + (size_t)bh * HD * Nn;   // [d][n]

    // DMA lane mapping: row-in-group r_l, swizzled global chunk jj
    const int r_l = lane >> 3;
    const int jj = (lane & 7) ^ r_l;
    const int xsw = l15 & 7;  // frag-read chunk XOR

    // P B-frag shuffle sources (R7-proven dest-side select)
    const int src0 = l15 + (quad & 1) * 32;
    const bool qhi = quad >= 2;

    const float SC = 0.18033688f;  // 0.125 * log2(e)

    for (int hx = 0; hx < 2; ++hx) {
        const int qt = hx ? (31 - p) : p;
        const int nkt = qt + 1;
        const int qrow = qt * 64 + wid * 16 + l15;

        bf16x8 qf[2];
#pragma unroll
        for (int st = 0; st < 2; ++st)
            qf[st] = __builtin_bit_cast(bf16x8,
                *(const uint4*)(qb + (size_t)qrow * HD + st * 32 + quad * 8));

        f32x4 oacc[4];
#pragma unroll
        for (int dt = 0; dt < 4; ++dt) oacc[dt] = zero4();
        float m_i = -3e38f, l_i = 0.f;

        // prologue: stage tile 0 into buf 0 (barrier protects prior reads)
        __syncthreads();
#pragma unroll
        for (int i = 0; i < 4; ++i) {
            int idx = wid * 4 + i;  // 0..15: 0-7 K, 8-15 V^T
            if (idx < 8) {
                const u16* g = kb + (size_t)(idx * 8 + r_l) * HD + jj * 8;
                async_copy16(g, &KsL[0][idx * 512]);
            } else {
                int ii = idx - 8;
                const u16* g = vt + (size_t)(ii * 8 + r_l) * Nn + jj * 8;
                async_copy16(g, &VtL[0][ii * 512]);
            }
        }

        for (int kt = 0; kt < nkt; ++kt) {
            __syncthreads();  // drains DMA for buf[kt&1]; fences prev reads
            if (kt + 1 < nkt) {
                const int nb = (kt + 1) & 1;
#pragma unroll
                for (int i = 0; i < 4; ++i) {
                    int idx = wid * 4 + i;
                    if (idx < 8) {
                        const u16* g = kb + (size_t)((kt + 1) * 64 + idx * 8 + r_l) * HD + jj * 8;
                        async_copy16(g, &KsL[nb][idx * 512]);
                    } else {
                        int ii = idx - 8;
                        const u16* g = vt + (size_t)(ii * 8 + r_l) * Nn + (kt + 1) * 64 + jj * 8;
                        async_copy16(g, &VtL[nb][ii * 512]);
                    }
                }
            }
            const u16* K = KsL[kt & 1];
            const u16* V = VtL[kt & 1];

            // S^T[key][q]: 4 key-tiles of 16
            f32x4 s[4];
#pragma unroll
            for (int t = 0; t < 4; ++t) {
                f32x4 a = zero4();
#pragma unroll
                for (int st = 0; st < 2; ++st) {
                    bf16x8 kf = ld_frag(&K[(t * 16 + l15) * 64 +
                                           ((st * 4 + quad) ^ xsw) * 8]);
                    a = __builtin_amdgcn_mfma_f32_16x16x32_bf16(kf, qf[st], a, 0, 0, 0);
                }
                s[t] = a;
            }

            // scale (log2 domain) + causal mask on diagonal tile
            const bool dn = (kt == qt);
#pragma unroll
            for (int t = 0; t < 4; ++t)
#pragma unroll
                for (int r = 0; r < 4; ++r) {
                    int key = kt * 64 + t * 16 + quad * 4 + r;
                    float v = s[t][r] * SC;
                    if (dn && key > qrow) v = -3e38f;
                    s[t][r] = v;
                }

            // online softmax: in-lane + 2 shuffles; exp2
            float mx = s[0][0];
#pragma unroll
            for (int t = 0; t < 4; ++t)
#pragma unroll
                for (int r = 0; r < 4; ++r) mx = fmaxf(mx, s[t][r]);
            mx = fmaxf(mx, __shfl_xor(mx, 16));
            mx = fmaxf(mx, __shfl_xor(mx, 32));
            float mn = fmaxf(m_i, mx);
            float alpha = exp2f(m_i - mn);
            m_i = mn;
            float rs = 0.f;
#pragma unroll
            for (int t = 0; t < 4; ++t)
#pragma unroll
                for (int r = 0; r < 4; ++r) {
                    float e = exp2f(s[t][r] - mn);
                    s[t][r] = e;
                    rs += e;
                }
            rs += __shfl_xor(rs, 16);
            rs += __shfl_xor(rs, 32);
            l_i = l_i * alpha + rs;
#pragma unroll
            for (int dt = 0; dt < 4; ++dt)
#pragma unroll
                for (int r = 0; r < 4; ++r) oacc[dt][r] *= alpha;

            // pack P; B-frags via both-candidate shuffle + dest-side select
            u32 pk[4][2];
#pragma unroll
            for (int t = 0; t < 4; ++t) {
                pk[t][0] = pack2(s[t][0], s[t][1]);
                pk[t][1] = pack2(s[t][2], s[t][3]);
            }
#pragma unroll
            for (int st = 0; st < 2; ++st) {
                u32 e0 = pk[2 * st][0],     e1 = pk[2 * st][1];
                u32 o0 = pk[2 * st + 1][0], o1 = pk[2 * st + 1][1];
                u32 A0 = __shfl(e0, src0),      B0 = __shfl(o0, src0);
                u32 A1 = __shfl(e1, src0),      B1 = __shfl(o1, src0);
                u32 A2 = __shfl(e0, src0 + 16), B2 = __shfl(o0, src0 + 16);
                u32 A3 = __shfl(e1, src0 + 16), B3 = __shfl(o1, src0 + 16);
                u32 U0 = qhi ? B0 : A0;
                u32 U1 = qhi ? B1 : A1;
                u32 U2 = qhi ? B2 : A2;
                u32 U3 = qhi ? B3 : A3;
                bf16x8 pf = __builtin_bit_cast(bf16x8, make_uint4(U0, U1, U2, U3));
#pragma unroll
                for (int dt = 0; dt < 4; ++dt) {
                    bf16x8 vf = ld_frag(&V[(dt * 16 + l15) * 64 +
                                           ((st * 4 + quad) ^ xsw) * 8]);
                    oacc[dt] = __builtin_amdgcn_mfma_f32_16x16x32_bf16(
                        vf, pf, oacc[dt], 0, 0, 0);
                }
            }
        }

        // epilogue: O^T C-layout col=q(lane), row=d(quad*4+r)
        float inv = 1.f / l_i;
#pragma unroll
        for (int dt = 0; dt < 4; ++dt) {
            ushort4 ov;
            ov.x = f2bf(oacc[dt][0] * inv);
            ov.y = f2bf(oacc[dt][1] * inv);
            ov.z = f2bf(oacc[dt][2] * inv);
            ov.w = f2bf(oacc[dt][3] * inv);
            *(ushort4*)&sabuf[((size_t)(b * Nn + qrow)) * Ee + h * 64 +
                              dt * 16 + quad * 4] = ov;
        }
    }
}

// ---------------------------------------------------------------------------
// Kernel 3: output projection, MFMA 32x32x16 (unchanged R8).
// ---------------------------------------------------------------------------
typedef float f32x16 __attribute__((ext_vector_type(16)));
__device__ __forceinline__ f32x16 zero16() {
    f32x16 z;
#pragma unroll
    for (int i = 0; i < 16; ++i) z[i] = 0.f;
    return z;
}

__global__ __launch_bounds__(256) void out_mfma(
    const u16* __restrict__ A, const u16* __restrict__ Wt,
    const float* __restrict__ bias, float* __restrict__ out)
{
    const int mt = blockIdx.x;  // 0..31
    const int nt = blockIdx.y;  // 0..15
    const int tid = threadIdx.x;
    const int lane = tid & 63, wid = tid >> 6;
    const int l31 = lane & 31, khalf = (lane >> 5) * 8;

    __shared__ u16 As[128][72];
    __shared__ u16 Bs[64][72];

    f32x16 acc[2];
    acc[0] = zero16(); acc[1] = zero16();

    const u16* ab = A + (size_t)mt * 128 * Ee;
    const int arow = tid >> 1, akh = (tid & 1) * 32;
    const int brow = tid >> 2, bc = (tid & 3) * 16;

    for (int k0 = 0; k0 < Ee; k0 += 64) {
        __syncthreads();
        {
            const u16* asrc = ab + (size_t)arow * Ee + k0 + akh;
#pragma unroll
            for (int j = 0; j < 4; ++j)
                *(uint4*)&As[arow][akh + 8 * j] = *(const uint4*)(asrc + 8 * j);
            const u16* bsrc = Wt + (size_t)(nt * 64 + brow) * 1024 + k0 + bc;
            *(uint4*)&Bs[brow][bc]     = *(const uint4*)(bsrc);
            *(uint4*)&Bs[brow][bc + 8] = *(const uint4*)(bsrc + 8);
        }
        __syncthreads();
#pragma unroll
        for (int kc = 0; kc < 4; ++kc) {
            bf16x8 af = ld_frag(&As[wid * 32 + l31][kc * 16 + khalf]);
#pragma unroll
            for (int ct = 0; ct < 2; ++ct) {
                bf16x8 bf = ld_frag(&Bs[ct * 32 + l31][kc * 16 + khalf]);
                acc[ct] = __builtin_amdgcn_mfma_f32_32x32x16_bf16(af, bf, acc[ct], 0, 0, 0);
            }
        }
    }

#pragma unroll
    for (int ct = 0; ct < 2; ++ct) {
        int col = nt * 64 + ct * 32 + l31;
        float bv = bias[col];
#pragma unroll
        for (int r = 0; r < 16; ++r) {
            int row_l = (r & 3) + 8 * (r >> 2) + 4 * (lane >> 5);
            int gm = mt * 128 + wid * 32 + row_l;
            out[(size_t)gm * Ee + col] = acc[ct][r] + bv;
        }
    }
}

// ---------------------------------------------------------------------------
extern "C" void kernel_launch(void* const* d_in, const int* in_sizes, int n_in,
                              void* d_out, int out_size, void* d_ws, size_t ws_size,
                              hipStream_t stream) {
    const float* x    = (const float*)d_in[0];  // [2,2048,1024] f32
    const float* Wqkv = (const float*)d_in[1];  // [16,1024,192] f32
    const float* bqkv = (const float*)d_in[2];  // [16,192] f32
    const float* Wout = (const float*)d_in[3];  // [1024,1024] f32
    const float* bout = (const float*)d_in[4];  // [1024] f32
    float* out = (float*)d_out;                 // [2,2048,1024] f32

    const size_t SZ = (size_t)Bz * Hh * Nn * HD;        // 4,194,304 elems
    const size_t NSA = (size_t)Bz * Nn * Ee;            // 4,194,304 elems
    const size_t NEED = (3 * SZ + NSA) * sizeof(u16);   // 32 MiB

    if (ws_size < NEED) {
        ws_diag<<<1, 1, 0, stream>>>(out, 20000.0f + (float)(ws_size >> 20));
        return;
    }

    u16* ws = (u16*)d_ws;
    u16* kbuf  = ws;
    u16* qbuf  = ws + SZ;
    u16* vbuf  = ws + 2 * SZ;
    u16* sabuf = ws + 3 * SZ;
    u16* wqkv_t = sabuf;             // 6 MB in dead sa region (until attn2)
    u16* wout_t = kbuf;              // 2 MB in dead k region (after attn2)
    u16* xbf    = (u16*)d_out;       // 8 MB scratch (until qkv done)
    u16* vtb    = (u16*)d_out + SZ;  // 8 MB scratch (until out_mfma)

    convert_x<<<2048, 256, 0, stream>>>(x, xbf);
    transpose_f32_bf16<<<dim3(16, 3, 16), 256, 0, stream>>>(Wqkv, wqkv_t, 1024, 192);
    qkv_mfma<<<dim3(64, 16), 256, 0, stream>>>(xbf, wqkv_t, bqkv, kbuf, qbuf, vbuf);
    transpose_v<<<dim3(32, 32), 256, 0, stream>>>(vbuf, vtb);
    attn2<<<dim3(16, 32), 256, 0, stream>>>(qbuf, kbuf, vtb, sabuf);
    transpose_f32_bf16<<<dim3(16, 16, 1), 256, 0, stream>>>(Wout, wout_t, 1024, 1024);
    out_mfma<<<dim3(32, 16), 256, 0, stream>>>(sabuf, wout_t, bout, out);
}